// Round 5
// baseline (143.961 us; speedup 1.0000x reference)
//
#include <hip/hip_runtime.h>
#include <math.h>

// ALCOVE cell: B=256, D=64, H=2048, O=32
// RHO=2, TAU=1, BETA=6.5, GAMMA=0, PHI=2, LAM_A=0.001, LAM_W=0.003
//
// R8: R7 (one block per b, 256 x 1024, sync-free across blocks) with
// intra-block software pipelining:
//   - areg (16 x float4 assoc) loads hoisted to the TOP of the kernel:
//     HBM latency hides under phase-1 distance compute (they were
//     barrier-trapped after phase 1 in R7).
//   - phase-1 ct reads as float2 (thread owns h=2t,2t+1): half the
//     vmem issue count, still coalesced.
//   - phase 3 split: coeff (LDS) -> barrier -> assoc stores (fire) ->
//     phase 4 g_att compute overlaps the 66 MB store drain.
// Summation orders identical to R7 -> bitwise-identical outputs.
//
// ws: ct [D*H] only (512 KB, L2-resident transpose of coords).

#define BB 256
#define DD 64
#define HH 2048
#define OO 32
#define BETA 6.5f
#define PHI 2.0f
#define LAM_A 0.001f
#define LAM_W 0.003f
#define NT0 256
#define NT 1024
#define NW (NT / 64)            // 16 waves
#define NCH (HH / (NT / 8))     // 16 assoc chunks per thread

__global__ __launch_bounds__(NT0) void k0_transpose(
    const float* __restrict__ coords, float* __restrict__ ct)
{
    int idx = blockIdx.x * NT0 + threadIdx.x;   // 0 .. D*H-1, ct-linear
    int d = idx >> 11;                          // / HH
    int h = idx & (HH - 1);
    ct[idx] = coords[h * DD + d];
}

__global__ __launch_bounds__(NT) void k_cell(
    const float* __restrict__ z,
    const float* __restrict__ one_hot,
    const float* __restrict__ att,
    const float* __restrict__ assoc,
    const float* __restrict__ coords,
    const float* __restrict__ ct,
    float* __restrict__ out)
{
    __shared__ float2 za[DD];           // (z_d, att_d)
    __shared__ float  s_loc[HH];        // 8 KB: similarity s
    __shared__ float  rc_loc[HH];       // 8 KB: r = -beta*s/(2d), then coeff
    __shared__ float  wredf[NW * OO];   // 2 KB: per-wave x_out partials
    __shared__ float  redf[NT];         // 4 KB: g_att reduction
    __shared__ float  gx_s[OO];

    const int b = blockIdx.x;
    const int t = threadIdx.x;
    const int o4 = t & 7;        // float4 column (o = o4*4 + comp)
    const int hl = t >> 3;       // 0..127

    // ---- phase 0: issue ALL assoc loads first (depend on nothing);
    //      they complete under phase-1 compute ----
    const float4* assoc4 = (const float4*)(assoc + (size_t)b * HH * OO);
    float4 areg[NCH];
    #pragma unroll
    for (int ch = 0; ch < NCH; ++ch)
        areg[ch] = assoc4[(ch * (NT / 8) + hl) * (OO / 4) + o4];

    if (t < DD)
        za[t] = make_float2(z[b * DD + t], att[b * DD + t]);
    __syncthreads();

    // ---- phase 1: distance/similarity, 2 h per thread via float2 ----
    {
        float S0 = 0.0f, S1 = 0.0f;
        const float2* ct2 = (const float2*)ct;       // ct[d][h] as float2
        #pragma unroll 16
        for (int d = 0; d < DD; ++d) {
            float2 p = za[d];                        // broadcast ds_read_b64
            float2 c = ct2[d * (HH / 2) + t];        // coalesced 512B/wave
            float d0 = p.x - c.x;
            float d1 = p.x - c.y;
            S0 = fmaf(p.y * d0, d0, S0);
            S1 = fmaf(p.y * d1, d1, S1);
        }
        S0 = S0 < 0.0f ? 0.0f : S0;
        S1 = S1 < 0.0f ? 0.0f : S1;
        float dd0 = sqrtf(S0), dd1 = sqrtf(S1);
        float sh0 = expf(-BETA * dd0), sh1 = expf(-BETA * dd1);
        float r0 = (dd0 > 0.0f) ? (-BETA * sh0 / (2.0f * dd0)) : 0.0f;
        float r1 = (dd1 > 0.0f) ? (-BETA * sh1 / (2.0f * dd1)) : 0.0f;
        ((float2*)s_loc)[t]  = make_float2(sh0, sh1);
        ((float2*)rc_loc)[t] = make_float2(r0, r1);
    }
    __syncthreads();

    // ---- phase 2: x_out from areg (loads long since landed) ----
    float4 acc = make_float4(0.f, 0.f, 0.f, 0.f);
    #pragma unroll
    for (int ch = 0; ch < NCH; ++ch) {
        int hloc = ch * (NT / 8) + hl;
        float s2 = s_loc[hloc];                      // 8-way broadcast, conflict-free
        float4 a = areg[ch];
        acc.x = fmaf(s2, a.x, acc.x);
        acc.y = fmaf(s2, a.y, acc.y);
        acc.z = fmaf(s2, a.z, acc.z);
        acc.w = fmaf(s2, a.w, acc.w);
    }
    // reduce over the 8 hl-rows inside each wave (lane bits 3..5)
    #pragma unroll
    for (int m = 8; m <= 32; m <<= 1) {
        acc.x += __shfl_xor(acc.x, m, 64);
        acc.y += __shfl_xor(acc.y, m, 64);
        acc.z += __shfl_xor(acc.z, m, 64);
        acc.w += __shfl_xor(acc.w, m, 64);
    }
    if ((t & 63) < 8) {                              // lane o4 of each wave
        int w = t >> 6;
        wredf[w * OO + o4 * 4 + 0] = acc.x;
        wredf[w * OO + o4 * 4 + 1] = acc.y;
        wredf[w * OO + o4 * 4 + 2] = acc.z;
        wredf[w * OO + o4 * 4 + 3] = acc.w;
    }
    __syncthreads();

    // ---- gx + output 0 (t < 32; o == t) ----
    if (t < OO) {
        float x = 0.0f;
        #pragma unroll
        for (int w = 0; w < NW; ++w)
            x += wredf[w * OO + t];                  // conflict-free rows
        float oh = one_hot[b * OO + t];
        float tmin = fminf(-1.0f, x);
        float tmax = fmaxf(1.0f, x);
        float teacher = tmin - oh * tmin + oh * tmax;
        gx_s[t] = (2.0f / OO) * (x - teacher);
        out[b * OO + t] = PHI * x;                   // output 0
    }
    __syncthreads();

    // ---- phase 3a: g_s -> coeff (LDS only, no stores yet) ----
    const float4 gxv = ((const float4*)gx_s)[o4];
    #pragma unroll
    for (int ch = 0; ch < NCH; ++ch) {
        int hloc = ch * (NT / 8) + hl;
        float4 a = areg[ch];
        float part = a.x * gxv.x + a.y * gxv.y + a.z * gxv.z + a.w * gxv.w;
        part += __shfl_xor(part, 1, 64);
        part += __shfl_xor(part, 2, 64);
        part += __shfl_xor(part, 4, 64);
        if (o4 == 0)
            rc_loc[hloc] *= part;                    // coeff = r * g_s
    }
    __syncthreads();                                 // rc_loc ready (LDS-only wait)

    // ---- phase 3b: fire assoc-update stores; they drain under phase 4 ----
    {
        float4* out_assoc4 = (float4*)(out + BB * OO + BB * DD)
                           + (size_t)b * HH * (OO / 4);
        #pragma unroll
        for (int ch = 0; ch < NCH; ++ch) {
            int hloc = ch * (NT / 8) + hl;
            float4 a = areg[ch];
            float w = LAM_W * s_loc[hloc];
            float4 na;
            na.x = fmaf(-w, gxv.x, a.x);
            na.y = fmaf(-w, gxv.y, a.y);
            na.z = fmaf(-w, gxv.z, a.z);
            na.w = fmaf(-w, gxv.w, a.w);
            out_assoc4[hloc * (OO / 4) + o4] = na;   // output 2
        }
    }

    // ---- phase 4: g_att compute overlapping store drain ----
    {
        const int lane = t & 63, wv = t >> 6;
        const float zd = za[lane].x;
        float ga = 0.0f;
        #pragma unroll 8
        for (int i = 0; i < HH / NW; ++i) {          // 128 h per wave
            int hloc = wv * (HH / NW) + i;
            float cf = rc_loc[hloc];                 // same-address broadcast
            float c = coords[(size_t)hloc * DD + lane];  // coalesced 256B line
            float diff = zd - c;
            ga = fmaf(cf * diff, diff, ga);
        }
        redf[t] = ga;
    }
    __syncthreads();
    if (t < DD) {
        float g = 0.0f;
        #pragma unroll
        for (int w = 0; w < NW; ++w)
            g += redf[w * 64 + t];                   // conflict-free rows
        float na = att[b * DD + t] - LAM_A * g;
        out[BB * OO + b * DD + t] = na > 0.0f ? na : 0.0f;   // output 1
    }
}

extern "C" void kernel_launch(void* const* d_in, const int* in_sizes, int n_in,
                              void* d_out, int out_size, void* d_ws, size_t ws_size,
                              hipStream_t stream) {
    const float* z       = (const float*)d_in[0];
    const float* one_hot = (const float*)d_in[1];
    const float* att     = (const float*)d_in[2];
    const float* assoc   = (const float*)d_in[3];
    const float* coords  = (const float*)d_in[4];
    float* out = (float*)d_out;

    float* ct = (float*)d_ws;                        // D*H floats

    k0_transpose<<<dim3((DD * HH) / NT0), dim3(NT0), 0, stream>>>(coords, ct);
    k_cell<<<dim3(BB), dim3(NT), 0, stream>>>(z, one_hot, att, assoc,
                                              coords, ct, out);
}

// Round 6
// 136.845 us; speedup vs baseline: 1.0520x; 1.0520x over previous
//
#include <hip/hip_runtime.h>
#include <math.h>

// ALCOVE cell: B=256, D=64, H=2048, O=32
// RHO=2, TAU=1, BETA=6.5, GAMMA=0, PHI=2, LAM_A=0.001, LAM_W=0.003
//
// R9: R7 base (one block per b, 256 x 1024, proven 44.4us) + two
// mechanism-verified pipeline fixes (R8 post-mortem: compiler sank the
// areg loads, VGPR 60->48, and the pre-barrier hoist was drained by
// __syncthreads' vmcnt(0)):
//   1) areg loads issued AFTER the za barrier, pinned live at end of
//      phase 1 via asm volatile("" :: "v"(..)) -> loads overlap phase-1
//      compute; phases 2/3 consume registers (assoc read once, truly).
//      Signal: VGPR ~110-128 (R7: 60).
//   2) phase 3: coeff (LDS) -> cheap barrier (nothing outstanding) ->
//      fire assoc stores -> phase 4 compute (no barrier between!) ->
//      LDS-only barrier (s_waitcnt lgkmcnt(0); s_barrier) -> out1.
//      The 66 MB store drain overlaps phase 4 + out1 + kernel end.
// Arithmetic/summation order identical to R7 -> bitwise-identical outputs.
//
// ws: ct [D*H] only (512 KB, L2-resident transpose of coords).

#define BB 256
#define DD 64
#define HH 2048
#define OO 32
#define BETA 6.5f
#define PHI 2.0f
#define LAM_A 0.001f
#define LAM_W 0.003f
#define NT0 256
#define NT 1024
#define NW (NT / 64)            // 16 waves
#define NCH (HH / (NT / 8))     // 16 assoc chunks per thread

__global__ __launch_bounds__(NT0) void k0_transpose(
    const float* __restrict__ coords, float* __restrict__ ct)
{
    int idx = blockIdx.x * NT0 + threadIdx.x;   // 0 .. D*H-1, ct-linear
    int d = idx >> 11;                          // / HH
    int h = idx & (HH - 1);
    ct[idx] = coords[h * DD + d];
}

__global__ __launch_bounds__(NT) void k_cell(
    const float* __restrict__ z,
    const float* __restrict__ one_hot,
    const float* __restrict__ att,
    const float* __restrict__ assoc,
    const float* __restrict__ coords,
    const float* __restrict__ ct,
    float* __restrict__ out)
{
    __shared__ float2 za[DD];           // (z_d, att_d)
    __shared__ float  s_loc[HH];        // 8 KB: similarity s
    __shared__ float  rc_loc[HH];       // 8 KB: r = -beta*s/(2d), then coeff
    __shared__ float  wredf[NW * OO];   // 2 KB: per-wave x_out partials
    __shared__ float  redf[NT];         // 4 KB: g_att reduction
    __shared__ float  gx_s[OO];

    const int b = blockIdx.x;
    const int t = threadIdx.x;
    const int o4 = t & 7;        // float4 column (o = o4*4 + comp)
    const int hl = t >> 3;       // 0..127

    if (t < DD)
        za[t] = make_float2(z[b * DD + t], att[b * DD + t]);
    __syncthreads();

    // ---- issue all 16 assoc loads NOW (after the barrier, so no drain);
    //      they complete under phase-1 compute; pinned live below ----
    const float4* assoc4 = (const float4*)(assoc + (size_t)b * HH * OO);
    float4 areg[NCH];
    #pragma unroll
    for (int ch = 0; ch < NCH; ++ch)
        areg[ch] = assoc4[(ch * (NT / 8) + hl) * (OO / 4) + o4];

    // ---- phase 1: distance/similarity for all 2048 h (R7 form) ----
    #pragma unroll
    for (int i = 0; i < HH / NT; ++i) {          // 2 rounds of 1024 h
        const int h = i * NT + t;
        float S = 0.0f;
        const float* ctp = ct + h;
        #pragma unroll 16
        for (int d = 0; d < DD; ++d) {
            float2 p = za[d];                    // broadcast ds_read_b64
            float c = ctp[d * HH];               // coalesced, L2-hit
            float diff = p.x - c;
            S = fmaf(p.y * diff, diff, S);
        }
        S = S < 0.0f ? 0.0f : S;
        float dd = sqrtf(S);
        float sh = expf(-BETA * dd);
        s_loc[h]  = sh;
        rc_loc[h] = (dd > 0.0f) ? (-BETA * sh / (2.0f * dd)) : 0.0f;
    }
    // pin areg live HERE: forces the loads issued above (not sunk into
    // phase 2/3) and waited-for at this point, after phase-1 compute.
    #pragma unroll
    for (int ch = 0; ch < NCH; ++ch)
        asm volatile("" :: "v"(areg[ch].x), "v"(areg[ch].y),
                           "v"(areg[ch].z), "v"(areg[ch].w));
    __syncthreads();

    // ---- phase 2: x_out from registers ----
    float4 acc = make_float4(0.f, 0.f, 0.f, 0.f);
    #pragma unroll
    for (int ch = 0; ch < NCH; ++ch) {
        int hloc = ch * (NT / 8) + hl;
        float s2 = s_loc[hloc];                  // 8-way broadcast, conflict-free
        float4 a = areg[ch];
        acc.x = fmaf(s2, a.x, acc.x);
        acc.y = fmaf(s2, a.y, acc.y);
        acc.z = fmaf(s2, a.z, acc.z);
        acc.w = fmaf(s2, a.w, acc.w);
    }
    // reduce over the 8 hl-rows inside each wave (lane bits 3..5)
    #pragma unroll
    for (int m = 8; m <= 32; m <<= 1) {
        acc.x += __shfl_xor(acc.x, m, 64);
        acc.y += __shfl_xor(acc.y, m, 64);
        acc.z += __shfl_xor(acc.z, m, 64);
        acc.w += __shfl_xor(acc.w, m, 64);
    }
    if ((t & 63) < 8) {                          // lane o4 of each wave
        int w = t >> 6;
        wredf[w * OO + o4 * 4 + 0] = acc.x;
        wredf[w * OO + o4 * 4 + 1] = acc.y;
        wredf[w * OO + o4 * 4 + 2] = acc.z;
        wredf[w * OO + o4 * 4 + 3] = acc.w;
    }
    __syncthreads();

    // ---- gx + output 0 (t < 32; o == t) ----
    if (t < OO) {
        float x = 0.0f;
        #pragma unroll
        for (int w = 0; w < NW; ++w)
            x += wredf[w * OO + t];              // conflict-free rows
        float oh = one_hot[b * OO + t];
        float tmin = fminf(-1.0f, x);
        float tmax = fmaxf(1.0f, x);
        float teacher = tmin - oh * tmin + oh * tmax;
        gx_s[t] = (2.0f / OO) * (x - teacher);
        out[b * OO + t] = PHI * x;               // output 0
    }
    __syncthreads();

    // ---- phase 3a: g_s -> coeff (LDS + shfl only, uses areg) ----
    const float4 gxv = ((const float4*)gx_s)[o4];
    #pragma unroll
    for (int ch = 0; ch < NCH; ++ch) {
        int hloc = ch * (NT / 8) + hl;
        float4 a = areg[ch];
        float part = a.x * gxv.x + a.y * gxv.y + a.z * gxv.z + a.w * gxv.w;
        part += __shfl_xor(part, 1, 64);
        part += __shfl_xor(part, 2, 64);
        part += __shfl_xor(part, 4, 64);
        if (o4 == 0)
            rc_loc[hloc] *= part;                // coeff = r * g_s
    }
    __syncthreads();    // cheap: no vmem outstanding; publishes rc_loc

    // ---- phase 3b: fire assoc-update stores (no wait) ----
    {
        float4* out_assoc4 = (float4*)(out + BB * OO + BB * DD)
                           + (size_t)b * HH * (OO / 4);
        #pragma unroll
        for (int ch = 0; ch < NCH; ++ch) {
            int hloc = ch * (NT / 8) + hl;
            float4 a = areg[ch];
            float w = LAM_W * s_loc[hloc];
            float4 na;
            na.x = fmaf(-w, gxv.x, a.x);
            na.y = fmaf(-w, gxv.y, a.y);
            na.z = fmaf(-w, gxv.z, a.z);
            na.w = fmaf(-w, gxv.w, a.w);
            out_assoc4[hloc * (OO / 4) + o4] = na;   // output 2
        }
    }

    // ---- phase 4: g_att compute; stores drain underneath (no barrier) ----
    {
        const int lane = t & 63, wv = t >> 6;
        const float zd = za[lane].x;
        float ga = 0.0f;
        #pragma unroll 8
        for (int i = 0; i < HH / NW; ++i) {      // 128 h per wave
            int hloc = wv * (HH / NW) + i;
            float cf = rc_loc[hloc];             // same-address broadcast
            float c = coords[(size_t)hloc * DD + lane];  // coalesced, L2-hit
            float diff = zd - c;
            ga = fmaf(cf * diff, diff, ga);
        }
        redf[t] = ga;
    }
    // LDS-only barrier: redf visibility without draining the assoc stores
    asm volatile("s_waitcnt lgkmcnt(0)\n\ts_barrier" ::: "memory");

    if (t < DD) {
        float g = 0.0f;
        #pragma unroll
        for (int w = 0; w < NW; ++w)
            g += redf[w * 64 + t];               // conflict-free rows
        float na = att[b * DD + t] - LAM_A * g;
        out[BB * OO + b * DD + t] = na > 0.0f ? na : 0.0f;   // output 1
    }
    // kernel end drains the assoc stores
}

extern "C" void kernel_launch(void* const* d_in, const int* in_sizes, int n_in,
                              void* d_out, int out_size, void* d_ws, size_t ws_size,
                              hipStream_t stream) {
    const float* z       = (const float*)d_in[0];
    const float* one_hot = (const float*)d_in[1];
    const float* att     = (const float*)d_in[2];
    const float* assoc   = (const float*)d_in[3];
    const float* coords  = (const float*)d_in[4];
    float* out = (float*)d_out;

    float* ct = (float*)d_ws;                    // D*H floats

    k0_transpose<<<dim3((DD * HH) / NT0), dim3(NT0), 0, stream>>>(coords, ct);
    k_cell<<<dim3(BB), dim3(NT), 0, stream>>>(z, one_hot, att, assoc,
                                              coords, ct, out);
}